// Round 3
// baseline (163.664 us; speedup 1.0000x reference)
//
#include <hip/hip_runtime.h>

#define NCH 64
#define LAG 5
#define H0 32
#define H1 32
#define TIN 2048
#define TOUT 2044
#define NBATCH 16

#define XSTRIDE 72   // ushorts per staged X row (144 B = 128 data + 16 pad)

typedef __attribute__((ext_vector_type(8))) short short8;    // 8 bf16 (4 VGPRs)
typedef __attribute__((ext_vector_type(4))) short short4v;   // 4 bf16 (2 VGPRs)
typedef __attribute__((ext_vector_type(4))) float f32x4;

__device__ __forceinline__ unsigned short f2bf(float f) {
    unsigned u = __float_as_uint(f);
    u += 0x7fffu + ((u >> 16) & 1u);     // RNE
    return (unsigned short)(u >> 16);
}

// ReLU + round-half-up bf16 pack: inputs are >= 0 after fmax, so u+0x8000
// then hi16 is round-half-up (max err 0.5 ulp, same bound as RNE).
// One v_perm_b32 extracts both hi16s: dst = [ua.b2, ua.b3, ub.b2, ub.b3].
__device__ __forceinline__ unsigned pack2bf_relu(float a, float b) {
    unsigned ua = __float_as_uint(fmaxf(a, 0.0f)) + 0x8000u;
    unsigned ub = __float_as_uint(fmaxf(b, 0.0f)) + 0x8000u;
    return __builtin_amdgcn_perm(ub, ua, 0x07060302u);   // src0=ub (idx 4-7), src1=ua (idx 0-3)
}

__device__ __forceinline__ short4v pack4bf_relu(const f32x4& v) {
    union { short4v s; unsigned u[2]; } cv;
    cv.u[0] = pack2bf_relu(v[0], v[1]);
    cv.u[1] = pack2bf_relu(v[2], v[3]);
    return cv.s;
}

// ---- fused prep: X -> padded bf16 image | W0 repack | W1 | W2 ----
__global__ __launch_bounds__(256) void prep_all(
    const float* __restrict__ X,  unsigned short* __restrict__ Xpad,
    const float* __restrict__ W0, unsigned short* __restrict__ W0b,
    const float* __restrict__ W1, unsigned short* __restrict__ W1b,
    const float* __restrict__ W2, unsigned short* __restrict__ W2b)
{
    const int bx = blockIdx.x;
    if (bx < 2048) {
        int j = bx * 256 + threadIdx.x;        // 524,288 float4-groups
        int row = j >> 4, seg = j & 15;
        float4 x = *(const float4*)(X + (size_t)j * 4);
        unsigned long long v = (unsigned long long)f2bf(x.x)
                             | ((unsigned long long)f2bf(x.y) << 16)
                             | ((unsigned long long)f2bf(x.z) << 32)
                             | ((unsigned long long)f2bf(x.w) << 48);
        *(unsigned long long*)(Xpad + (size_t)row * XSTRIDE + seg * 4) = v;
    } else if (bx < 2560) {
        int j = (bx - 2048) * 256 + threadIdx.x;   // 131072 = 64n*32h*64c
        int nh = j >> 6, c = j & 63;
        const float* src = W0 + (size_t)j * LAG;
        unsigned short* dst = W0b + nh * 320 + c;
        #pragma unroll
        for (int l = 0; l < LAG; ++l) dst[l * 64] = f2bf(src[l]);
    } else if (bx < 2592) {
        int i = ((bx - 2560) * 256 + threadIdx.x) * 8;
        float4 a = *(const float4*)(W1 + i);
        float4 b = *(const float4*)(W1 + i + 4);
        unsigned long long v0 = (unsigned long long)f2bf(a.x)
                              | ((unsigned long long)f2bf(a.y) << 16)
                              | ((unsigned long long)f2bf(a.z) << 32)
                              | ((unsigned long long)f2bf(a.w) << 48);
        unsigned long long v1 = (unsigned long long)f2bf(b.x)
                              | ((unsigned long long)f2bf(b.y) << 16)
                              | ((unsigned long long)f2bf(b.z) << 32)
                              | ((unsigned long long)f2bf(b.w) << 48);
        *(unsigned long long*)(W1b + i)     = v0;
        *(unsigned long long*)(W1b + i + 4) = v1;
    } else {
        int i = threadIdx.x * 8;
        float4 a = *(const float4*)(W2 + i);
        float4 b = *(const float4*)(W2 + i + 4);
        unsigned long long v0 = (unsigned long long)f2bf(a.x)
                              | ((unsigned long long)f2bf(a.y) << 16)
                              | ((unsigned long long)f2bf(a.z) << 32)
                              | ((unsigned long long)f2bf(a.w) << 48);
        unsigned long long v1 = (unsigned long long)f2bf(b.x)
                              | ((unsigned long long)f2bf(b.y) << 16)
                              | ((unsigned long long)f2bf(b.z) << 32)
                              | ((unsigned long long)f2bf(b.w) << 48);
        *(unsigned long long*)(W2b + i)     = v0;
        *(unsigned long long*)(W2b + i + 4) = v1;
    }
}

// ---- main: block = 256-pos tile x 4 nets; wave = net; register-only L1/L2 ----
// R2 post-mortem: wave COUNT, not per-wave ILP, is the latency-hiding resource
// (2-nets/wave halved waves -> MfmaUtil 43->34%). So: keep R1's 1-net/wave
// structure but cut unified regs to <=128 so 4 waves/SIMD fit (16 waves/CU vs 8):
// only the nf=0 half of the L0 weights stays in registers (40 VGPRs); the nf=1
// half streams from L2 per chunk (W0b is 1.3 MB -> L2-resident; ~670 MB of L2
// reads = ~19 us pipe, overlapped with LDS ~25 us + matrix ~24 us).
// An empty-asm launder of the stream pointer per chunk blocks LICM from
// hoisting all 10 fragments back into registers.
__global__ __launch_bounds__(256, 4) void mlp_mfma(
    const unsigned short* __restrict__ Xpad,
    const unsigned short* __restrict__ W0b,
    const unsigned short* __restrict__ W1b,
    const unsigned short* __restrict__ W2b,
    const float* __restrict__ b0, const float* __restrict__ b1,
    const float* __restrict__ b2, float* __restrict__ out)
{
    __shared__ __align__(16) unsigned short xs[37 * 512];        // 37,888 B
    __shared__ __align__(8)  unsigned short yt[256][4];          //  2,048 B (bf16)

    const int tileid = blockIdx.x;
    const int ng     = blockIdx.y;
    const int b      = tileid >> 3;
    const int t0     = (tileid & 7) * 256;
    const int tid    = threadIdx.x;
    const int wave   = tid >> 6;
    const int lane   = tid & 63;
    const int quad   = lane >> 4;
    const int l15    = lane & 15;

    // ---- stage X tile: direct global->LDS DMA, 1 KB per instruction ----
    {
        const char* srcb = (const char*)(Xpad + (size_t)(b * TIN + t0) * XSTRIDE);
        #pragma unroll 1
        for (int i = wave; i < 37; i += 4) {
            __builtin_amdgcn_global_load_lds(
                (const __attribute__((address_space(1))) unsigned int*)(srcb + i * 1024 + lane * 16),
                (__attribute__((address_space(3))) unsigned int*)((char*)xs + i * 1024),
                16, 0, 0);
        }
    }

    // ---- per-wave net: nf=0 weight half in regs; nf=1 half streamed from L2 ----
    const int n = ng * 4 + wave;
    short8 B0r[10];
    const unsigned short* wp0 = W0b + (n * H0 + l15) * (NCH * LAG) + quad * 8;
    const unsigned short* wp1 = W0b + (n * H0 + 16 + l15) * (NCH * LAG) + quad * 8;
    #pragma unroll
    for (int ks = 0; ks < 10; ++ks)
        B0r[ks] = *(const short8*)(wp0 + ks * 32);

    short4v A1[2][2];
    #pragma unroll
    for (int of = 0; of < 2; ++of)
        #pragma unroll
        for (int kf = 0; kf < 2; ++kf)
            A1[of][kf] = *(const short4v*)(W1b + (n * H1 + of * 16 + l15) * H0 + kf * 16 + quad * 4);
    short4v A2[2];
    #pragma unroll
    for (int kf = 0; kf < 2; ++kf)
        A2[kf] = *(const short4v*)(W2b + n * H1 + kf * 16 + quad * 4);
    f32x4 b0q[2], b1q[2];
    #pragma unroll
    for (int nf = 0; nf < 2; ++nf) b0q[nf] = *(const f32x4*)(b0 + (size_t)n * H0 + nf * 16 + quad * 4);
    #pragma unroll
    for (int of = 0; of < 2; ++of) b1q[of] = *(const f32x4*)(b1 + (size_t)n * H1 + of * 16 + quad * 4);
    const float b2s = b2[n];

    __syncthreads();   // drains global_load_lds (vmcnt) + weight loads

    const int vmax = (t0 == 1792) ? 251 : 255;

    #pragma unroll 1
    for (int chunk = 0; chunk < 8; ++chunk) {
        // launder the stream pointer so LICM can't hoist the 10 nf=1
        // fragment loads (40 VGPRs) out of the chunk loop
        const unsigned short* wp1c = wp1;
        asm volatile("" : "+v"(wp1c));

        int rowoff[2];
        #pragma unroll
        for (int mf = 0; mf < 2; ++mf) {
            int i = chunk * 32 + mf * 16 + l15;
            i = i < vmax ? i : vmax;
            rowoff[mf] = i * XSTRIDE + quad * 8;
        }

        // ---- layer 0 (transposed): acc[mf][nf] = C[row=h][col=pos] ----
        f32x4 acc[2][2];
        #pragma unroll
        for (int mf = 0; mf < 2; ++mf) {
            acc[mf][0] = b0q[0];
            acc[mf][1] = b0q[1];
        }
        __builtin_amdgcn_s_setprio(1);
        #pragma unroll
        for (int ks = 0; ks < 10; ++ks) {
            const int xoff = (ks >> 1) * XSTRIDE + (ks & 1) * 32;
            short8 Wl  = *(const short8*)(wp1c + ks * 32);            // L2 stream
            short8 Xf0 = *(const short8*)&xs[rowoff[0] + xoff];       // B-op: n=pos
            short8 Xf1 = *(const short8*)&xs[rowoff[1] + xoff];
            acc[0][0] = __builtin_amdgcn_mfma_f32_16x16x32_bf16(B0r[ks], Xf0, acc[0][0], 0, 0, 0);
            acc[1][0] = __builtin_amdgcn_mfma_f32_16x16x32_bf16(B0r[ks], Xf1, acc[1][0], 0, 0, 0);
            acc[0][1] = __builtin_amdgcn_mfma_f32_16x16x32_bf16(Wl,      Xf0, acc[0][1], 0, 0, 0);
            acc[1][1] = __builtin_amdgcn_mfma_f32_16x16x32_bf16(Wl,      Xf1, acc[1][1], 0, 0, 0);
        }
        __builtin_amdgcn_s_setprio(0);

        // ---- layers 1+2: register-only ----
        #pragma unroll
        for (int mf = 0; mf < 2; ++mf) {
            short4v Bh0 = pack4bf_relu(acc[mf][0]);   // h 0..15
            short4v Bh1 = pack4bf_relu(acc[mf][1]);   // h 16..31

            f32x4 D1[2] = { b1q[0], b1q[1] };
            D1[0] = __builtin_amdgcn_mfma_f32_16x16x16bf16_1k(A1[0][0], Bh0, D1[0], 0, 0, 0);
            D1[0] = __builtin_amdgcn_mfma_f32_16x16x16bf16_1k(A1[0][1], Bh1, D1[0], 0, 0, 0);
            D1[1] = __builtin_amdgcn_mfma_f32_16x16x16bf16_1k(A1[1][0], Bh0, D1[1], 0, 0, 0);
            D1[1] = __builtin_amdgcn_mfma_f32_16x16x16bf16_1k(A1[1][1], Bh1, D1[1], 0, 0, 0);

            short4v Bg0 = pack4bf_relu(D1[0]);        // o 0..15
            short4v Bg1 = pack4bf_relu(D1[1]);        // o 16..31

            f32x4 D2 = (f32x4){ b2s, b2s, b2s, b2s };
            D2 = __builtin_amdgcn_mfma_f32_16x16x16bf16_1k(A2[0], Bg0, D2, 0, 0, 0);
            D2 = __builtin_amdgcn_mfma_f32_16x16x16bf16_1k(A2[1], Bg1, D2, 0, 0, 0);

            if (quad == 0)
                yt[chunk * 32 + mf * 16 + l15][wave] = f2bf(D2[0]);
        }
    }
    __syncthreads();

    // ---- coalesced output: bf16 yt -> float4 per thread ----
    int t = t0 + tid;
    if (t < TOUT) {
        ushort4 v = *(const ushort4*)yt[tid];
        float4 o;
        o.x = __uint_as_float((unsigned)v.x << 16);
        o.y = __uint_as_float((unsigned)v.y << 16);
        o.z = __uint_as_float((unsigned)v.z << 16);
        o.w = __uint_as_float((unsigned)v.w << 16);
        *(float4*)&out[((size_t)(b * TOUT + t)) * NCH + ng * 4] = o;
    }
}

extern "C" void kernel_launch(void* const* d_in, const int* in_sizes, int n_in,
                              void* d_out, int out_size, void* d_ws, size_t ws_size,
                              hipStream_t stream)
{
    const float* X  = (const float*)d_in[0];
    const float* W0 = (const float*)d_in[1];
    const float* b0 = (const float*)d_in[2];
    const float* W1 = (const float*)d_in[3];
    const float* b1 = (const float*)d_in[4];
    const float* W2 = (const float*)d_in[5];
    const float* b2 = (const float*)d_in[6];
    float* out = (float*)d_out;

    // ws layout: Xpad 4,718,592 B (+8,192 cushion for tail over-copy), then weights
    unsigned short* Xpad = (unsigned short*)d_ws;
    unsigned short* W0b  = (unsigned short*)((char*)d_ws + 4726784);   // 1,310,720 B
    unsigned short* W1b  = (unsigned short*)((char*)d_ws + 6037504);   //   131,072 B
    unsigned short* W2b  = (unsigned short*)((char*)d_ws + 6168576);   //     4,096 B

    prep_all<<<2593, 256, 0, stream>>>(X, Xpad, W0, W0b, W1, W1b, W2, W2b);
    mlp_mfma<<<dim3(128, 16), 256, 0, stream>>>(Xpad, W0b, W1b, W2b, b0, b1, b2, out);
}

// Round 4
// 116.368 us; speedup vs baseline: 1.4064x; 1.4064x over previous
//
#include <hip/hip_runtime.h>

#define NCH 64
#define LAG 5
#define H0 32
#define H1 32
#define TIN 2048
#define TOUT 2044
#define NBATCH 16

#define XSTRIDE 72   // ushorts per staged X row (144 B = 128 data + 16 pad)

typedef __attribute__((ext_vector_type(8))) short short8;    // 8 bf16 (4 VGPRs)
typedef __attribute__((ext_vector_type(4))) short short4v;   // 4 bf16 (2 VGPRs)
typedef __attribute__((ext_vector_type(4))) float f32x4;

__device__ __forceinline__ unsigned short f2bf(float f) {
    unsigned u = __float_as_uint(f);
    u += 0x7fffu + ((u >> 16) & 1u);     // RNE
    return (unsigned short)(u >> 16);
}

// ReLU + round-half-up bf16 pack: inputs are >= 0 after fmax, so u+0x8000
// then hi16 is round-half-up (max err 0.5 ulp, same bound as RNE).
// One v_perm_b32 extracts both hi16s: dst = [ua.b2, ua.b3, ub.b2, ub.b3].
__device__ __forceinline__ unsigned pack2bf_relu(float a, float b) {
    unsigned ua = __float_as_uint(fmaxf(a, 0.0f)) + 0x8000u;
    unsigned ub = __float_as_uint(fmaxf(b, 0.0f)) + 0x8000u;
    return __builtin_amdgcn_perm(ub, ua, 0x07060302u);   // src0=ub (idx 4-7), src1=ua (idx 0-3)
}

__device__ __forceinline__ short4v pack4bf_relu(const f32x4& v) {
    union { short4v s; unsigned u[2]; } cv;
    cv.u[0] = pack2bf_relu(v[0], v[1]);
    cv.u[1] = pack2bf_relu(v[2], v[3]);
    return cv.s;
}

// ---- fused prep: X -> padded bf16 image | W0 repack | W1 | W2 ----
__global__ __launch_bounds__(256) void prep_all(
    const float* __restrict__ X,  unsigned short* __restrict__ Xpad,
    const float* __restrict__ W0, unsigned short* __restrict__ W0b,
    const float* __restrict__ W1, unsigned short* __restrict__ W1b,
    const float* __restrict__ W2, unsigned short* __restrict__ W2b)
{
    const int bx = blockIdx.x;
    if (bx < 2048) {
        int j = bx * 256 + threadIdx.x;        // 524,288 float4-groups
        int row = j >> 4, seg = j & 15;
        float4 x = *(const float4*)(X + (size_t)j * 4);
        unsigned long long v = (unsigned long long)f2bf(x.x)
                             | ((unsigned long long)f2bf(x.y) << 16)
                             | ((unsigned long long)f2bf(x.z) << 32)
                             | ((unsigned long long)f2bf(x.w) << 48);
        *(unsigned long long*)(Xpad + (size_t)row * XSTRIDE + seg * 4) = v;
    } else if (bx < 2560) {
        int j = (bx - 2048) * 256 + threadIdx.x;   // 131072 = 64n*32h*64c
        int nh = j >> 6, c = j & 63;
        const float* src = W0 + (size_t)j * LAG;
        unsigned short* dst = W0b + nh * 320 + c;
        #pragma unroll
        for (int l = 0; l < LAG; ++l) dst[l * 64] = f2bf(src[l]);
    } else if (bx < 2592) {
        int i = ((bx - 2560) * 256 + threadIdx.x) * 8;
        float4 a = *(const float4*)(W1 + i);
        float4 b = *(const float4*)(W1 + i + 4);
        unsigned long long v0 = (unsigned long long)f2bf(a.x)
                              | ((unsigned long long)f2bf(a.y) << 16)
                              | ((unsigned long long)f2bf(a.z) << 32)
                              | ((unsigned long long)f2bf(a.w) << 48);
        unsigned long long v1 = (unsigned long long)f2bf(b.x)
                              | ((unsigned long long)f2bf(b.y) << 16)
                              | ((unsigned long long)f2bf(b.z) << 32)
                              | ((unsigned long long)f2bf(b.w) << 48);
        *(unsigned long long*)(W1b + i)     = v0;
        *(unsigned long long*)(W1b + i + 4) = v1;
    } else {
        int i = threadIdx.x * 8;
        float4 a = *(const float4*)(W2 + i);
        float4 b = *(const float4*)(W2 + i + 4);
        unsigned long long v0 = (unsigned long long)f2bf(a.x)
                              | ((unsigned long long)f2bf(a.y) << 16)
                              | ((unsigned long long)f2bf(a.z) << 32)
                              | ((unsigned long long)f2bf(a.w) << 48);
        unsigned long long v1 = (unsigned long long)f2bf(b.x)
                              | ((unsigned long long)f2bf(b.y) << 16)
                              | ((unsigned long long)f2bf(b.z) << 32)
                              | ((unsigned long long)f2bf(b.w) << 48);
        *(unsigned long long*)(W2b + i)     = v0;
        *(unsigned long long*)(W2b + i + 4) = v1;
    }
}

// ---- main: block = 256-pos tile x 4 nets; wave = net; register-only L1/L2 ----
// R3 post-mortem settled the model: R1's 43% MfmaUtil is intra-wave tail
// serialization (pack->L1->pack->L2, ~300cy, near-zero matrix issue), not
// occupancy (R3: more waves + longer critical path = worse) and not ILP-per-wave
// at the cost of waves (R2). Fix: software-pipeline the chunk loop. Two named
// accumulator sets aA/aB rotate; each scheduling region = { L0(chunk c+1) ,
// TAIL(chunk c) } in ONE branch-free basic block so the list scheduler
// interleaves the independent big-MFMA/ds_read stream with the tail chain.
// yt widened to [256][8]: non-quad0 lanes store to a dump column (never read)
// to keep the region branch-free. setprio removed (its side effects would
// fence exactly the reordering we want). launch_bounds(256,2): we're at
// 2 waves/SIMD anyway; give regalloc room for the extra acc set.
__global__ __launch_bounds__(256, 2) void mlp_mfma(
    const unsigned short* __restrict__ Xpad,
    const unsigned short* __restrict__ W0b,
    const unsigned short* __restrict__ W1b,
    const unsigned short* __restrict__ W2b,
    const float* __restrict__ b0, const float* __restrict__ b1,
    const float* __restrict__ b2, float* __restrict__ out)
{
    __shared__ __align__(16) unsigned short xs[37 * 512];        // 37,888 B
    __shared__ __align__(16) unsigned short yt[256][8];          //  4,096 B (bf16)

    const int tileid = blockIdx.x;
    const int ng     = blockIdx.y;
    const int b      = tileid >> 3;
    const int t0     = (tileid & 7) * 256;
    const int tid    = threadIdx.x;
    const int wave   = tid >> 6;
    const int lane   = tid & 63;
    const int quad   = lane >> 4;
    const int l15    = lane & 15;
    const int colw   = wave + (quad ? 4 : 0);   // quad!=0 -> dump column (never read)

    // ---- stage X tile: direct global->LDS DMA, 1 KB per instruction ----
    {
        const char* srcb = (const char*)(Xpad + (size_t)(b * TIN + t0) * XSTRIDE);
        #pragma unroll 1
        for (int i = wave; i < 37; i += 4) {
            __builtin_amdgcn_global_load_lds(
                (const __attribute__((address_space(1))) unsigned int*)(srcb + i * 1024 + lane * 16),
                (__attribute__((address_space(3))) unsigned int*)((char*)xs + i * 1024),
                16, 0, 0);
        }
    }

    // ---- per-wave net: weight fragments (pre-repacked bf16), loaded once ----
    const int n = ng * 4 + wave;
    short8 B0[10][2];
    const unsigned short* wp0 = W0b + (n * H0 + l15) * (NCH * LAG) + quad * 8;
    #pragma unroll
    for (int ks = 0; ks < 10; ++ks) {
        B0[ks][0] = *(const short8*)(wp0 + ks * 32);
        B0[ks][1] = *(const short8*)(wp0 + 16 * (NCH * LAG) + ks * 32);
    }
    short4v A1[2][2];
    #pragma unroll
    for (int of = 0; of < 2; ++of)
        #pragma unroll
        for (int kf = 0; kf < 2; ++kf)
            A1[of][kf] = *(const short4v*)(W1b + (n * H1 + of * 16 + l15) * H0 + kf * 16 + quad * 4);
    short4v A2[2];
    #pragma unroll
    for (int kf = 0; kf < 2; ++kf)
        A2[kf] = *(const short4v*)(W2b + n * H1 + kf * 16 + quad * 4);
    f32x4 b0q[2], b1q[2];
    #pragma unroll
    for (int nf = 0; nf < 2; ++nf) b0q[nf] = *(const f32x4*)(b0 + (size_t)n * H0 + nf * 16 + quad * 4);
    #pragma unroll
    for (int of = 0; of < 2; ++of) b1q[of] = *(const f32x4*)(b1 + (size_t)n * H1 + of * 16 + quad * 4);
    const float b2s = b2[n];

    __syncthreads();   // drains global_load_lds (vmcnt) + weight loads

    const int vmax = (t0 == 1792) ? 251 : 255;

    // L0: layer-0 conv for one 32-pos chunk -> A[mf][nf] (40 big MFMAs, 20 ds_reads)
    auto L0 = [&](f32x4 (&A)[2][2], int c) {
        int i0 = c * 32 + l15;       i0 = i0 < vmax ? i0 : vmax;
        int i1 = c * 32 + 16 + l15;  i1 = i1 < vmax ? i1 : vmax;
        const int ro0 = i0 * XSTRIDE + quad * 8;
        const int ro1 = i1 * XSTRIDE + quad * 8;
        A[0][0] = b0q[0]; A[0][1] = b0q[1];
        A[1][0] = b0q[0]; A[1][1] = b0q[1];
        #pragma unroll
        for (int ks = 0; ks < 10; ++ks) {
            const int xoff = (ks >> 1) * XSTRIDE + (ks & 1) * 32;
            short8 Xf0 = *(const short8*)&xs[ro0 + xoff];   // B-op: n=pos
            short8 Xf1 = *(const short8*)&xs[ro1 + xoff];
            A[0][0] = __builtin_amdgcn_mfma_f32_16x16x32_bf16(B0[ks][0], Xf0, A[0][0], 0, 0, 0);
            A[0][1] = __builtin_amdgcn_mfma_f32_16x16x32_bf16(B0[ks][1], Xf0, A[0][1], 0, 0, 0);
            A[1][0] = __builtin_amdgcn_mfma_f32_16x16x32_bf16(B0[ks][0], Xf1, A[1][0], 0, 0, 0);
            A[1][1] = __builtin_amdgcn_mfma_f32_16x16x32_bf16(B0[ks][1], Xf1, A[1][1], 0, 0, 0);
        }
    };

    // TAIL: layers 1+2 for one chunk, register-only, branch-free store
    auto TAIL = [&](f32x4 (&A)[2][2], int c) {
        #pragma unroll
        for (int mf = 0; mf < 2; ++mf) {
            short4v Bh0 = pack4bf_relu(A[mf][0]);   // h 0..15
            short4v Bh1 = pack4bf_relu(A[mf][1]);   // h 16..31

            f32x4 D1[2] = { b1q[0], b1q[1] };
            D1[0] = __builtin_amdgcn_mfma_f32_16x16x16bf16_1k(A1[0][0], Bh0, D1[0], 0, 0, 0);
            D1[0] = __builtin_amdgcn_mfma_f32_16x16x16bf16_1k(A1[0][1], Bh1, D1[0], 0, 0, 0);
            D1[1] = __builtin_amdgcn_mfma_f32_16x16x16bf16_1k(A1[1][0], Bh0, D1[1], 0, 0, 0);
            D1[1] = __builtin_amdgcn_mfma_f32_16x16x16bf16_1k(A1[1][1], Bh1, D1[1], 0, 0, 0);

            short4v Bg0 = pack4bf_relu(D1[0]);      // o 0..15
            short4v Bg1 = pack4bf_relu(D1[1]);      // o 16..31

            f32x4 D2 = (f32x4){ b2s, b2s, b2s, b2s };
            D2 = __builtin_amdgcn_mfma_f32_16x16x16bf16_1k(A2[0], Bg0, D2, 0, 0, 0);
            D2 = __builtin_amdgcn_mfma_f32_16x16x16bf16_1k(A2[1], Bg1, D2, 0, 0, 0);

            yt[c * 32 + mf * 16 + l15][colw] = f2bf(D2[0]);
        }
    };

    // ---- 2-stage software pipeline: TAIL(c) overlaps L0(c+1) ----
    f32x4 aA[2][2], aB[2][2];
    L0(aA, 0);
    #pragma unroll 1
    for (int cp = 0; cp < 3; ++cp) {
        L0(aB, 2 * cp + 1); TAIL(aA, 2 * cp);
        L0(aA, 2 * cp + 2); TAIL(aB, 2 * cp + 1);
    }
    L0(aB, 7); TAIL(aA, 6);
    TAIL(aB, 7);

    __syncthreads();

    // ---- coalesced output: bf16 yt -> float4 per thread ----
    int t = t0 + tid;
    if (t < TOUT) {
        ushort4 v = *(const ushort4*)yt[tid];   // cols 0-3 = real data
        float4 o;
        o.x = __uint_as_float((unsigned)v.x << 16);
        o.y = __uint_as_float((unsigned)v.y << 16);
        o.z = __uint_as_float((unsigned)v.z << 16);
        o.w = __uint_as_float((unsigned)v.w << 16);
        *(float4*)&out[((size_t)(b * TOUT + t)) * NCH + ng * 4] = o;
    }
}

extern "C" void kernel_launch(void* const* d_in, const int* in_sizes, int n_in,
                              void* d_out, int out_size, void* d_ws, size_t ws_size,
                              hipStream_t stream)
{
    const float* X  = (const float*)d_in[0];
    const float* W0 = (const float*)d_in[1];
    const float* b0 = (const float*)d_in[2];
    const float* W1 = (const float*)d_in[3];
    const float* b1 = (const float*)d_in[4];
    const float* W2 = (const float*)d_in[5];
    const float* b2 = (const float*)d_in[6];
    float* out = (float*)d_out;

    // ws layout: Xpad 4,718,592 B (+8,192 cushion for tail over-copy), then weights
    unsigned short* Xpad = (unsigned short*)d_ws;
    unsigned short* W0b  = (unsigned short*)((char*)d_ws + 4726784);   // 1,310,720 B
    unsigned short* W1b  = (unsigned short*)((char*)d_ws + 6037504);   //   131,072 B
    unsigned short* W2b  = (unsigned short*)((char*)d_ws + 6168576);   //     4,096 B

    prep_all<<<2593, 256, 0, stream>>>(X, Xpad, W0, W0b, W1, W1b, W2, W2b);
    mlp_mfma<<<dim3(128, 16), 256, 0, stream>>>(Xpad, W0b, W1b, W2b, b0, b1, b2, out);
}